// Round 4
// baseline (103.700 us; speedup 1.0000x reference)
//
#include <hip/hip_runtime.h>
#include <hip/hip_cooperative_groups.h>
#include <math.h>

namespace cg = cooperative_groups;

#define BS   16
#define NQ   128
#define NCLS 3
#define T    480
#define P    72
#define BN   (BS * NQ)      // 2048
#define TROW (5 + 2 * P)    // 149
#define NBLK 256
#define NTHR 512
#define BNB  (BN / NBLK)    // 8 bn per block in phase 2

// ws layout (bytes):
//   MD  double[16][T] @ 0      (61440)
//     rows 0..6  : m_j  = sum_valid lam^j            (j=0..6)
//     rows 7..10 : sx_k = -2 * sum_valid tx*lam^k    (k=0..3)
//     rows 11..14: sy_k = -2 * sum_valid ty*lam^k    (k=0..3)
//     row  15    : Q    = sum_valid (tx^2 + ty^2)
//   EF  float[6][T]   @ 61440  (11520): ly, uy, lx, ux, per, id
#define MD_OFF_B 0
#define EF_OFF_B 61440

// Single cooperative kernel:
//   phase 1: global wave g (= blockIdx*8 + waveid) < 480 computes moments for
//            target t=g (coalesced row reads, fp64 accum, 64-lane butterfly).
//   grid.sync()
//   phase 2: block handles BNB bn's; thread = t; 16-term fp64 dot per (bn,t).
// 256 blocks x 512 threads with launch_bounds(512,2): 1 block/CU co-resident,
// cooperative launch always fits.
__global__ __launch_bounds__(NTHR, 2) void fused_kernel(const float* __restrict__ logits,
                                                        const float* __restrict__ curves,
                                                        const float* __restrict__ targets,
                                                        double* __restrict__ MD,
                                                        float* __restrict__ EF,
                                                        float* __restrict__ out) {
    __shared__ float wavemin[NTHR / 64];
    int tid  = threadIdx.x;
    int lane = tid & 63;
    int wid  = tid >> 6;
    int g    = blockIdx.x * (NTHR / 64) + wid;   // global wave id

    // ---------------- phase 1: moments for t = g ----------------
    if (g < T) {
        int t = g;
        const float* row = targets + (size_t)t * TROW;
        float ly = row[1], uy = row[2], lx = row[3], ux = row[4];
        float dx = ux - lx, dy = uy - ly;
        float nrm = sqrtf(dx * dx + dy * dy);

        double v[17];
#pragma unroll
        for (int i = 0; i < 17; ++i) v[i] = 0.0;

        for (int p = lane; p < P; p += 64) {
            float tx = row[5 + p];          // coalesced across lanes
            float ty = row[5 + P + p];
            if (tx >= 0.0f) {
                float lamf = dx * (tx - lx) + dy * (ty - ly);
                lamf = lamf / nrm / nrm;    // match reference: dot/nrm/nrm
                double L   = (double)lamf;
                double txd = (double)tx, tyd = (double)ty;
                double lp = 1.0;
#pragma unroll
                for (int j = 0; j < 7; ++j) {
                    v[j] += lp;
                    if (j < 4) {
                        v[7 + j]  += txd * lp;
                        v[11 + j] += tyd * lp;
                    }
                    lp *= L;
                }
                v[15] += txd * txd + tyd * tyd;
                v[16] += 1.0;               // valid count
            }
        }

#pragma unroll
        for (int off = 32; off > 0; off >>= 1) {
#pragma unroll
            for (int i = 0; i < 17; ++i) v[i] += __shfl_down(v[i], off);
        }

        if (lane == 0) {
#pragma unroll
            for (int j = 0; j < 7; ++j) MD[j * T + t] = v[j];
#pragma unroll
            for (int k = 0; k < 4; ++k) {
                MD[(7 + k) * T + t]  = -2.0 * v[7 + k];
                MD[(11 + k) * T + t] = -2.0 * v[11 + k];
            }
            MD[15 * T + t] = v[15];
            EF[0 * T + t] = ly;
            EF[1 * T + t] = uy;
            EF[2 * T + t] = lx;
            EF[3 * T + t] = ux;
            EF[4 * T + t] = (float)v[16];
            EF[5 * T + t] = row[0];         // class id
        }
    }

    cg::this_grid().sync();

    // ---------------- phase 2: cost ----------------
    int t   = tid;
    int bn0 = blockIdx.x * BNB;

    // per_min over all 480 t; w[t] = sqrt(per_min/per) (total cancels in ref)
    float per = (t < T) ? EF[4 * T + t] : 1e30f;
    float pm = per;
#pragma unroll
    for (int off = 32; off > 0; off >>= 1) pm = fminf(pm, __shfl_xor(pm, off));
    if (lane == 0) wavemin[wid] = pm;
    __syncthreads();
    float per_min = wavemin[0];
#pragma unroll
    for (int i = 1; i < NTHR / 64; ++i) per_min = fminf(per_min, wavemin[i]);

    if (t >= T) return;
    float w = sqrtf(per_min / per);

    double m[16];
#pragma unroll
    for (int r = 0; r < 16; ++r) m[r] = MD[r * T + t];   // coalesced
    float ly = EF[0 * T + t], uy = EF[1 * T + t];
    float lx = EF[2 * T + t], ux = EF[3 * T + t];
    int   id = (int)EF[5 * T + t];

#pragma unroll
    for (int j = 0; j < BNB; ++j) {
        int bn = bn0 + j;
        const float* ob = curves + (size_t)bn * 8;       // uniform -> s_load
        float o0 = ob[0], o1 = ob[1], o2 = ob[2], o3 = ob[3];
        float o4 = ob[4], o5 = ob[5], o6 = ob[6], o7 = ob[7];
        float a0 = o2, a1 = o3 - o4 - o5 - o2, a2 = o5, a3 = o4;
        float b0 = o0, b1 = o1 - o6 - o7 - o0, b2 = o7, b3 = o6;

        double A0 = a0, A1 = a1, A2 = a2, A3 = a3;
        double B0 = b0, B1 = b1, B2 = b2, B3 = b3;
        double acc = m[15]
            + (A0 * A0 + B0 * B0) * m[0]
            + 2.0 * (A0 * A1 + B0 * B1) * m[1]
            + (2.0 * (A0 * A2 + B0 * B2) + A1 * A1 + B1 * B1) * m[2]
            + 2.0 * (A0 * A3 + A1 * A2 + B0 * B3 + B1 * B2) * m[3]
            + (2.0 * (A1 * A3 + B1 * B3) + A2 * A2 + B2 * B2) * m[4]
            + 2.0 * (A2 * A3 + B2 * B3) * m[5]
            + (A3 * A3 + B3 * B3) * m[6]
            + A0 * m[7]  + A1 * m[8]  + A2 * m[9]  + A3 * m[10]
            + B0 * m[11] + B1 * m[12] + B2 * m[13] + B3 * m[14];

        const float* lg = logits + (size_t)bn * NCLS;    // uniform -> s_load
        float l0 = lg[0], l1 = lg[1], l2 = lg[2];
        float mx = fmaxf(l0, fmaxf(l1, l2));
        float e0 = __expf(l0 - mx), e1 = __expf(l1 - mx), e2 = __expf(l2 - mx);
        float inv = 1.0f / (e0 + e1 + e2);
        float prob = (id == 0) ? e0 * inv : ((id == 1) ? e1 * inv : e2 * inv);

        float cp = (float)acc * w * 0.1f;
        float cl = 0.5f * (fabsf(b0 - ly) + fabsf(a0 - lx));   // |ob0-ly|+|ob2-lx|
        float cu = 0.5f * (fabsf(o1 - uy) + fabsf(o3 - ux));   // |ob1-uy|+|ob3-ux|
        out[(size_t)bn * T + t] = -prob + cp + cl + cu;        // coalesced
    }
}

extern "C" void kernel_launch(void* const* d_in, const int* in_sizes, int n_in,
                              void* d_out, int out_size, void* d_ws, size_t ws_size,
                              hipStream_t stream) {
    const float* logits  = (const float*)d_in[0];  // (16,128,3)
    const float* curves  = (const float*)d_in[1];  // (16,128,8)
    const float* targets = (const float*)d_in[2];  // (480,149)
    float* out = (float*)d_out;
    char*  ws  = (char*)d_ws;

    double* MD = (double*)(ws + MD_OFF_B);
    float*  EF = (float*) (ws + EF_OFF_B);

    void* args[] = { (void*)&logits, (void*)&curves, (void*)&targets,
                     (void*)&MD, (void*)&EF, (void*)&out };
    hipLaunchCooperativeKernel((void*)fused_kernel, dim3(NBLK), dim3(NTHR),
                               args, 0, stream);
}

// Round 5
// 66.574 us; speedup vs baseline: 1.5577x; 1.5577x over previous
//
#include <hip/hip_runtime.h>
#include <math.h>

#define BS   16
#define NQ   128
#define NCLS 3
#define T    480
#define P    72
#define BN   (BS * NQ)      // 2048
#define TROW (5 + 2 * P)    // 149
#define BNB  4              // bn per block in cost kernel

// ws layout (bytes):
//   MD  double[16][T] @ 0      (61440)
//     rows 0..6  : m_j  = sum_valid lam^j            (j=0..6)
//     rows 7..10 : sx_k = -2 * sum_valid tx*lam^k    (k=0..3)
//     rows 11..14: sy_k = -2 * sum_valid ty*lam^k    (k=0..3)
//     row  15    : Q    = sum_valid (tx^2 + ty^2)
//   EF  float[6][T]   @ 61440  (11520): ly, uy, lx, ux, per, id
#define MD_OFF_B 0
#define EF_OFF_B 61440

// One block (1 wave) per target t: coalesced row reads, fp64 moment
// accumulation, wave butterfly reduction.
__global__ __launch_bounds__(64) void moments_kernel(const float* __restrict__ targets,
                                                     double* __restrict__ MD,
                                                     float* __restrict__ EF) {
    int t    = blockIdx.x;
    int lane = threadIdx.x;
    const float* row = targets + (size_t)t * TROW;
    float ly = row[1], uy = row[2], lx = row[3], ux = row[4];
    float dx = ux - lx, dy = uy - ly;
    float nrm = sqrtf(dx * dx + dy * dy);

    double v[17];
#pragma unroll
    for (int i = 0; i < 17; ++i) v[i] = 0.0;

    for (int p = lane; p < P; p += 64) {
        float tx = row[5 + p];          // coalesced across lanes
        float ty = row[5 + P + p];
        if (tx >= 0.0f) {
            float lamf = dx * (tx - lx) + dy * (ty - ly);
            lamf = lamf / nrm / nrm;    // match reference: dot/nrm/nrm
            double L   = (double)lamf;
            double txd = (double)tx, tyd = (double)ty;
            double lp = 1.0;
#pragma unroll
            for (int j = 0; j < 7; ++j) {
                v[j] += lp;
                if (j < 4) {
                    v[7 + j]  += txd * lp;
                    v[11 + j] += tyd * lp;
                }
                lp *= L;
            }
            v[15] += txd * txd + tyd * tyd;
            v[16] += 1.0;               // per-target valid count
        }
    }

    // 64-lane butterfly reduction of 17 doubles
#pragma unroll
    for (int off = 32; off > 0; off >>= 1) {
#pragma unroll
        for (int i = 0; i < 17; ++i) v[i] += __shfl_down(v[i], off);
    }

    if (lane == 0) {
#pragma unroll
        for (int j = 0; j < 7; ++j) MD[j * T + t] = v[j];
#pragma unroll
        for (int k = 0; k < 4; ++k) {
            MD[(7 + k) * T + t]  = -2.0 * v[7 + k];
            MD[(11 + k) * T + t] = -2.0 * v[11 + k];
        }
        MD[15 * T + t] = v[15];
        EF[0 * T + t] = ly;
        EF[1 * T + t] = uy;
        EF[2 * T + t] = lx;
        EF[3 * T + t] = ux;
        EF[4 * T + t] = (float)v[16];
        EF[5 * T + t] = row[0];         // class id
    }
}

// thread = t, block = BNB bn's. Per-bn prep (coeffs + softmax) inlined;
// quadratic-form terms folded directly into the 16-term fp64 dot.
__global__ __launch_bounds__(512) void cost_kernel(const float* __restrict__ logits,
                                                   const float* __restrict__ curves,
                                                   const double* __restrict__ MD,
                                                   const float* __restrict__ EF,
                                                   float* __restrict__ out) {
    __shared__ float wavemin[8];
    int t    = threadIdx.x;
    int bn0  = blockIdx.x * BNB;
    int lane = t & 63;
    int wid  = t >> 6;

    // per_min across all 480 t (block covers all t, so this is global).
    // w[t] = sqrt(total/per)/max(sqrt(total/per)) = sqrt(per_min/per)
    float per = (t < T) ? EF[4 * T + t] : 1e30f;
    float pm = per;
#pragma unroll
    for (int off = 32; off > 0; off >>= 1) pm = fminf(pm, __shfl_xor(pm, off));
    if (lane == 0) wavemin[wid] = pm;
    __syncthreads();
    float per_min = wavemin[0];
#pragma unroll
    for (int i = 1; i < 8; ++i) per_min = fminf(per_min, wavemin[i]);

    if (t >= T) return;
    float w = sqrtf(per_min / per);

    double m[16];
#pragma unroll
    for (int r = 0; r < 16; ++r) m[r] = MD[r * T + t];   // coalesced
    float ly = EF[0 * T + t], uy = EF[1 * T + t];
    float lx = EF[2 * T + t], ux = EF[3 * T + t];
    int   id = (int)EF[5 * T + t];

#pragma unroll
    for (int j = 0; j < BNB; ++j) {
        int bn = bn0 + j;
        const float* ob = curves + (size_t)bn * 8;       // uniform -> s_load
        float o0 = ob[0], o1 = ob[1], o2 = ob[2], o3 = ob[3];
        float o4 = ob[4], o5 = ob[5], o6 = ob[6], o7 = ob[7];
        float a0 = o2, a1 = o3 - o4 - o5 - o2, a2 = o5, a3 = o4;
        float b0 = o0, b1 = o1 - o6 - o7 - o0, b2 = o7, b3 = o6;

        double A0 = a0, A1 = a1, A2 = a2, A3 = a3;
        double B0 = b0, B1 = b1, B2 = b2, B3 = b3;
        double acc = m[15]
            + (A0 * A0 + B0 * B0) * m[0]
            + 2.0 * (A0 * A1 + B0 * B1) * m[1]
            + (2.0 * (A0 * A2 + B0 * B2) + A1 * A1 + B1 * B1) * m[2]
            + 2.0 * (A0 * A3 + A1 * A2 + B0 * B3 + B1 * B2) * m[3]
            + (2.0 * (A1 * A3 + B1 * B3) + A2 * A2 + B2 * B2) * m[4]
            + 2.0 * (A2 * A3 + B2 * B3) * m[5]
            + (A3 * A3 + B3 * B3) * m[6]
            + A0 * m[7]  + A1 * m[8]  + A2 * m[9]  + A3 * m[10]
            + B0 * m[11] + B1 * m[12] + B2 * m[13] + B3 * m[14];

        const float* lg = logits + (size_t)bn * NCLS;    // uniform -> s_load
        float l0 = lg[0], l1 = lg[1], l2 = lg[2];
        float mx = fmaxf(l0, fmaxf(l1, l2));
        float e0 = __expf(l0 - mx), e1 = __expf(l1 - mx), e2 = __expf(l2 - mx);
        float inv = 1.0f / (e0 + e1 + e2);
        float prob = (id == 0) ? e0 * inv : ((id == 1) ? e1 * inv : e2 * inv);

        float cp = (float)acc * w * 0.1f;
        float cl = 0.5f * (fabsf(b0 - ly) + fabsf(a0 - lx));   // |ob0-ly|+|ob2-lx|
        float cu = 0.5f * (fabsf(o1 - uy) + fabsf(o3 - ux));   // |ob1-uy|+|ob3-ux|
        out[(size_t)bn * T + t] = -prob + cp + cl + cu;        // coalesced
    }
}

extern "C" void kernel_launch(void* const* d_in, const int* in_sizes, int n_in,
                              void* d_out, int out_size, void* d_ws, size_t ws_size,
                              hipStream_t stream) {
    const float* logits  = (const float*)d_in[0];  // (16,128,3)
    const float* curves  = (const float*)d_in[1];  // (16,128,8)
    const float* targets = (const float*)d_in[2];  // (480,149)
    float* out = (float*)d_out;
    char*  ws  = (char*)d_ws;

    double* MD = (double*)(ws + MD_OFF_B);
    float*  EF = (float*) (ws + EF_OFF_B);

    moments_kernel<<<T, 64, 0, stream>>>(targets, MD, EF);
    cost_kernel<<<BN / BNB, 512, 0, stream>>>(logits, curves, MD, EF, out);
}